// Round 4
// baseline (158.977 us; speedup 1.0000x reference)
//
#include <hip/hip_runtime.h>

#define NPTS 4096
#define NEDGE 8064
#define M0f 0.05f
#define KMAXD2 7938
#define MCAP 128
#define LISTCAP 2048
#define PAIRCAP 160

typedef unsigned long long u64;

__device__ inline float waveSum(float x) {
  for (int m = 32; m >= 1; m >>= 1) x += __shfl_xor(x, m);
  return x;
}

__device__ inline int isqrt_i(int x) {  // exact floor sqrt for 0 <= x < 2^20
  int r = (int)sqrtf((float)x);
  if ((r + 1) * (r + 1) <= x) r++;
  else if (r * r > x) r--;
  return r;
}

__device__ inline u64 shfl64(u64 x, int src) {
  int lo = __shfl((int)(unsigned)(x & 0xffffffffull), src);
  int hi = __shfl((int)(unsigned)(x >> 32), src);
  return ((u64)(unsigned)hi << 32) | (u64)(unsigned)lo;
}

// ---------------- Kernel 1: DTM ----------------
// grid (256, B), block 1024 (16 waves). One wave per query point.
__global__ __launch_bounds__(1024) void dtm_kernel(const float* __restrict__ win,
                                                   float* __restrict__ fout) {
  __shared__ float P0[64][65];
  __shared__ float P1[64][65];
  __shared__ float P2[64][65];
  int b = blockIdx.y;
  const float* w = win + b * NPTS;
  int tid = threadIdx.x, lane = tid & 63, wv = tid >> 6;

  // Build per-row inclusive prefix sums of w, w*j, w*j^2 (query-independent).
  for (int rr = 0; rr < 4; ++rr) {
    int r = (wv << 2) | rr;
    float x0 = w[(r << 6) | lane];
    float fl = (float)lane;
    float x1 = x0 * fl, x2 = x1 * fl;
    for (int d = 1; d < 64; d <<= 1) {
      float t0 = __shfl_up(x0, d);
      float t1 = __shfl_up(x1, d);
      float t2 = __shfl_up(x2, d);
      if (lane >= d) { x0 += t0; x1 += t1; x2 += t2; }
    }
    P0[r][lane] = x0; P1[r][lane] = x1; P2[r][lane] = x2;
  }
  __syncthreads();

  float sumw = waveSum(P0[lane][63]);
  float thr = M0f * sumw;

  int q = blockIdx.x * 16 + wv;
  int qi = q >> 6, qj = q & 63;
  int di = qi - lane;          // lane == point-row index
  int disq = di * di;

  // Binary search smallest k with F(k) >= thr.
  int lo = -1, hi = KMAXD2;
  float Flo = 0.f;
  while (hi - lo > 1) {
    int mid = (lo + hi) >> 1;
    float s0 = 0.f;
    int rem = mid - disq;
    if (rem >= 0) {
      int r = isqrt_i(rem);
      int l0 = qj - r; l0 = l0 < 0 ? 0 : l0;
      int h0 = qj + r; h0 = h0 > 63 ? 63 : h0;
      s0 = P0[lane][h0] - (l0 > 0 ? P0[lane][l0 - 1] : 0.f);
    }
    float F = waveSum(s0);
    if (F >= thr) hi = mid; else { lo = mid; Flo = F; }
  }
  int kstar = hi;
  float Fm = Flo;

  // G = sum of w*k over k <= kstar-1
  float g = 0.f;
  {
    int rem = (kstar - 1) - disq;
    if (rem >= 0) {
      int r = isqrt_i(rem);
      int l0 = qj - r; l0 = l0 < 0 ? 0 : l0;
      int h0 = qj + r; h0 = h0 > 63 ? 63 : h0;
      float S0 = P0[lane][h0] - (l0 > 0 ? P0[lane][l0 - 1] : 0.f);
      float S1 = P1[lane][h0] - (l0 > 0 ? P1[lane][l0 - 1] : 0.f);
      float S2 = P2[lane][h0] - (l0 > 0 ? P2[lane][l0 - 1] : 0.f);
      float fq = (float)qj;
      g = (float)disq * S0 + fq * fq * S0 - 2.f * fq * S1 + S2;
    }
  }
  float G = waveSum(g);
  float val = (G + (thr - Fm) * (float)kstar) / thr;
  val = val < 0.f ? 0.f : val;
  float res = (224.f / 63.f) * sqrtf(val);
  if (lane == 0) fout[b * NPTS + q] = res;
}

// ---------------- Kernel 2: PH0 via basin contraction ----------------
__device__ inline void bitonic_sort(u64* a, int npad, int tid) {
  for (int k = 2; k <= npad; k <<= 1) {
    for (int j = k >> 1; j > 0; j >>= 1) {
      for (int i = tid; i < npad; i += 1024) {
        int ixj = i ^ j;
        if (ixj > i) {
          u64 x = a[i], y = a[ixj];
          bool up = ((i & k) == 0);
          if (up ? (x > y) : (x < y)) { a[i] = y; a[ixj] = x; }
        }
      }
      __syncthreads();
    }
  }
}

__global__ __launch_bounds__(1024) void ph_kernel(const float* __restrict__ fin,
                                                  int* __restrict__ np_out,
                                                  float2* __restrict__ pairs_out) {
  __shared__ float sf[NPTS];
  __shared__ __align__(16) int srep[NPTS];    // later aliased as u64 slist[LISTCAP]
  __shared__ __align__(16) int sbasin[NPTS];  // later aliased as u64 slist2[LISTCAP]
  __shared__ float smu[MCAP];
  __shared__ int sminv[MCAP];
  __shared__ float2 spairs[PAIRCAP];
  __shared__ int c_m, c_l1, c_l2, c_np;
  __shared__ unsigned fminb, fmaxb;

  int b = blockIdx.x;
  int tid = threadIdx.x;
  if (tid == 0) { c_m = 0; c_l1 = 0; c_l2 = 0; c_np = 0; fminb = 0x7f800000u; fmaxb = 0u; }
  if (tid < MCAP) { smu[tid] = 3.0e38f; sminv[tid] = tid; }
  __syncthreads();

  for (int v = tid; v < NPTS; v += 1024) {
    float x = fin[b * NPTS + v];
    sf[v] = x;
    atomicMin(&fminb, __float_as_uint(x));  // f >= 0: uint order == float order
    atomicMax(&fmaxb, __float_as_uint(x));
  }
  __syncthreads();

  // steepest-descent pointers (lexicographic (f, index) tie-break)
  for (int v = tid; v < NPTS; v += 1024) {
    int vi = v >> 6, vj = v & 63;
    float bf = sf[v]; int bi = v;
    if (vj > 0)  { float fn = sf[v - 1];  int n = v - 1;  if (fn < bf || (fn == bf && n < bi)) { bf = fn; bi = n; } }
    if (vj < 63) { float fn = sf[v + 1];  int n = v + 1;  if (fn < bf || (fn == bf && n < bi)) { bf = fn; bi = n; } }
    if (vi > 0)  { float fn = sf[v - 64]; int n = v - 64; if (fn < bf || (fn == bf && n < bi)) { bf = fn; bi = n; } }
    if (vi < 63) { float fn = sf[v + 64]; int n = v + 64; if (fn < bf || (fn == bf && n < bi)) { bf = fn; bi = n; } }
    srep[v] = bi;
  }
  __syncthreads();

  // pointer jumping to basin minima (2^12 >= any path length)
  for (int it = 0; it < 12; ++it) {
    for (int v = tid; v < NPTS; v += 1024) srep[v] = srep[srep[v]];
    __syncthreads();
  }

  // compact basin ids at minima
  for (int v = tid; v < NPTS; v += 1024) {
    if (srep[v] == v) {
      int id = atomicAdd(&c_m, 1);
      if (id < MCAP) { sbasin[v] = id; smu[id] = sf[v]; sminv[id] = v; }
      else sbasin[v] = MCAP - 1;
    }
  }
  __syncthreads();
  for (int v = tid; v < NPTS; v += 1024) {
    if (srep[v] != v) sbasin[v] = sbasin[srep[v]];
  }
  __syncthreads();

  // cross edges -> slist (aliases srep, now dead). key=(a<<8|b) pair, w in low bits.
  u64* slist = (u64*)srep;
  for (int e = tid; e < NEDGE; e += 1024) {
    int u, v2;
    if (e < 4032) { int i = e / 63; int j = e - i * 63; u = (i << 6) | j; v2 = u + 1; }
    else          { int e2 = e - 4032; u = e2; v2 = u + 64; }
    int bu = sbasin[u], bv = sbasin[v2];
    if (bu != bv) {
      float wgt = fmaxf(sf[u], sf[v2]);
      int a = bu < bv ? bu : bv, bb = bu < bv ? bv : bu;
      unsigned key = (unsigned)((a << 8) | bb);
      int slot = atomicAdd(&c_l1, 1);
      if (slot < LISTCAP) slist[slot] = ((u64)key << 32) | (u64)__float_as_uint(wgt);
    }
  }
  __syncthreads();
  int n1 = c_l1; if (n1 > LISTCAP) n1 = LISTCAP;
  int npad1 = 1; while (npad1 < n1) npad1 <<= 1;
  if (n1 == 0) npad1 = 0;
  for (int i = n1 + tid; i < npad1; i += 1024) slist[i] = ~0ull;
  __syncthreads();
  bitonic_sort(slist, npad1, tid);  // by (pair, w): min-w first per pair

  // dedup: keep first of each pair group -> slist2 (aliases sbasin, now dead), re-keyed (w<<32|pair)
  u64* slist2 = (u64*)sbasin;
  for (int i = tid; i < n1; i += 1024) {
    u64 cur = slist[i];
    if (i == 0 || (slist[i - 1] >> 32) != (cur >> 32)) {
      int slot = atomicAdd(&c_l2, 1);
      slist2[slot] = ((cur & 0xffffffffull) << 32) | (cur >> 32);
    }
  }
  __syncthreads();
  int n2 = c_l2;
  int npad2 = 1; while (npad2 < n2) npad2 <<= 1;
  if (n2 == 0) npad2 = 0;
  for (int i = n2 + tid; i < npad2; i += 1024) slist2[i] = ~0ull;
  __syncthreads();
  bitonic_sort(slist2, npad2, tid);  // by weight ascending

  // serial Kruskal, wave 0, parents/mu/rootvert in registers via shfl
  int lane = tid & 63;
  if (tid < 64) {
    int p0 = lane, p1 = 64 + lane;
    float mu0 = smu[lane], mu1 = smu[64 + lane];
    int rv0 = sminv[lane], rv1 = sminv[64 + lane];
    int np = 0;
    for (int base = 0; base < n2; base += 64) {
      u64 ev = (base + lane < n2) ? slist2[base + lane] : ~0ull;
      int cnt = n2 - base; if (cnt > 64) cnt = 64;
      for (int s = 0; s < cnt; ++s) {
        u64 e = shfl64(ev, s);
        unsigned wb = (unsigned)(e >> 32);
        int key = (int)(e & 0xffffull);
        int a = key >> 8, bb = key & 255;
        // find with path-halving (wave-uniform); hard-bounded for hang safety
        int ra = a;
        for (int g1 = 0; g1 < 200; ++g1) {
          int pa = __shfl((ra < 64) ? p0 : p1, ra & 63);
          if (pa == ra) break;
          int ga = __shfl((pa < 64) ? p0 : p1, pa & 63);
          if (lane == (ra & 63)) { if (ra < 64) p0 = ga; else p1 = ga; }
          ra = ga;
        }
        int rb = bb;
        for (int g2 = 0; g2 < 200; ++g2) {
          int pb2 = __shfl((rb < 64) ? p0 : p1, rb & 63);
          if (pb2 == rb) break;
          int gb = __shfl((pb2 < 64) ? p0 : p1, pb2 & 63);
          if (lane == (rb & 63)) { if (rb < 64) p0 = gb; else p1 = gb; }
          rb = gb;
        }
        if (ra != rb) {
          float mua = __shfl((ra < 64) ? mu0 : mu1, ra & 63);
          float mub = __shfl((rb < 64) ? mu0 : mu1, rb & 63);
          int rva = __shfl((ra < 64) ? rv0 : rv1, ra & 63);
          int rvb = __shfl((rb < 64) ? rv0 : rv1, rb & 63);
          bool aeld = (mua < mub) || (mua == mub && rva <= rvb);
          int eld = aeld ? ra : rb, yng = aeld ? rb : ra;
          float byoung = aeld ? mub : mua;
          if (lane == (yng & 63)) { if (yng < 64) p0 = eld; else p1 = eld; }
          if (lane == 0 && np < PAIRCAP - 1) spairs[np] = make_float2(byoung, __uint_as_float(wb));
          np++;
        }
      }
    }
    if (np > PAIRCAP - 1) np = PAIRCAP - 1;
    if (lane == 0) {
      spairs[np] = make_float2(__uint_as_float(fminb), __uint_as_float(fmaxb));  // essential pair
      c_np = np + 1;
    }
  }
  __syncthreads();
  int totp = c_np;
  if (tid == 0) np_out[b] = totp;
  for (int i = tid; i < totp; i += 1024) pairs_out[b * PAIRCAP + i] = spairs[i];
}

// ---------------- Kernel 3: landscape + MLP ----------------
__global__ __launch_bounds__(256) void land_mlp_kernel(const int* __restrict__ np_in,
                                                       const float2* __restrict__ pairs_in,
                                                       const float* __restrict__ Wg,
                                                       const float* __restrict__ bg,
                                                       const float* __restrict__ Wfc,
                                                       const float* __restrict__ bfc,
                                                       float* __restrict__ out) {
  __shared__ float land[2][50];
  __shared__ float xs[2][50];
  __shared__ float2 sp[2][PAIRCAP];
  __shared__ int snp[2];
  int tid = threadIdx.x;
  if (tid < 2) snp[tid] = np_in[tid];
  for (int i = tid; i < 2 * PAIRCAP; i += 256) sp[i / PAIRCAP][i % PAIRCAP] = pairs_in[i];
  __syncthreads();

  if (tid < 50) {
    int b = tid / 25, t = tid % 25;
    float tv = 1.875f * (float)t;  // linspace(0,45,25)
    float top1 = 0.f, top2 = 0.f;
    int n = snp[b];
    for (int i = 0; i < n; ++i) {
      float2 p = sp[b][i];
      float tri = fminf(tv - p.x, p.y - tv);
      tri = fmaxf(tri, 0.f);
      if (tri > top1) { top2 = top1; top1 = tri; }
      else if (tri > top2) top2 = tri;
    }
    land[b][t] = top1;
    land[b][25 + t] = top2;
  }
  __syncthreads();
  if (tid < 100) {
    int b = tid / 50, o = tid % 50;
    float acc = bg[o];
    for (int k = 0; k < 50; ++k) acc += land[b][k] * Wg[o * 50 + k];
    xs[b][o] = acc;
  }
  __syncthreads();
  if (tid < 50) out[20 + tid] = fabsf(xs[0][tid]) + fabsf(xs[1][tid]);
  if (tid >= 64 && tid < 84) {
    int t2 = tid - 64;
    int b = t2 / 10, c = t2 % 10;
    float acc = bfc[c];
    for (int o = 0; o < 50; ++o) acc += fmaxf(xs[b][o], 0.f) * Wfc[c * 50 + o];
    out[b * 10 + c] = acc;
  }
}

extern "C" void kernel_launch(void* const* d_in, const int* in_sizes, int n_in,
                              void* d_out, int out_size, void* d_ws, size_t ws_size,
                              hipStream_t stream) {
  (void)in_sizes; (void)n_in; (void)out_size; (void)ws_size;
  const float* input = (const float*)d_in[0];
  const float* Wg  = (const float*)d_in[1];
  const float* bg  = (const float*)d_in[2];
  const float* Wfc = (const float*)d_in[3];
  const float* bfc = (const float*)d_in[4];
  float* out = (float*)d_out;

  float*  f_ws     = (float*)d_ws;                              // 2*4096 f32
  int*    np_ws    = (int*)((char*)d_ws + 8192 * 4);            // 2 ints
  float2* pairs_ws = (float2*)((char*)d_ws + 8192 * 4 + 64);    // 2*PAIRCAP float2

  dtm_kernel<<<dim3(256, 2), 1024, 0, stream>>>(input, f_ws);
  ph_kernel<<<dim3(2), 1024, 0, stream>>>(f_ws, np_ws, pairs_ws);
  land_mlp_kernel<<<1, 256, 0, stream>>>(np_ws, pairs_ws, Wg, bg, Wfc, bfc, out);
}

// Round 5
// 111.875 us; speedup vs baseline: 1.4210x; 1.4210x over previous
//
#include <hip/hip_runtime.h>

#define NPTS 4096
#define NEDGE 8064
#define M0f 0.05f
#define KMAXD2 7938
#define IDCAP 90          // basin-id clamp; triangular pair table needs IDCAP*(IDCAP-1)/2 <= 4096
#define LISTCAP 2048
#define PAIRCAP 160

typedef unsigned long long u64;

__device__ inline float waveSum(float x) {
  for (int m = 32; m >= 1; m >>= 1) x += __shfl_xor(x, m);
  return x;
}

__device__ inline int isqrt_i(int x) {  // exact floor sqrt for 0 <= x < 2^20
  int r = (int)sqrtf((float)x);
  if ((r + 1) * (r + 1) <= x) r++;
  else if (r * r > x) r--;
  return r;
}

// ---------------- Kernel 1: DTM ----------------
// grid (256, B), block 1024 (16 waves). One wave per query point.
__global__ __launch_bounds__(1024) void dtm_kernel(const float* __restrict__ win,
                                                   float* __restrict__ fout) {
  __shared__ float P0[64][65];
  __shared__ float P1[64][65];
  __shared__ float P2[64][65];
  int b = blockIdx.y;
  const float* w = win + b * NPTS;
  int tid = threadIdx.x, lane = tid & 63, wv = tid >> 6;

  // Build per-row inclusive prefix sums of w, w*j, w*j^2 (query-independent).
  for (int rr = 0; rr < 4; ++rr) {
    int r = (wv << 2) | rr;
    float x0 = w[(r << 6) | lane];
    float fl = (float)lane;
    float x1 = x0 * fl, x2 = x1 * fl;
    for (int d = 1; d < 64; d <<= 1) {
      float t0 = __shfl_up(x0, d);
      float t1 = __shfl_up(x1, d);
      float t2 = __shfl_up(x2, d);
      if (lane >= d) { x0 += t0; x1 += t1; x2 += t2; }
    }
    P0[r][lane] = x0; P1[r][lane] = x1; P2[r][lane] = x2;
  }
  __syncthreads();

  float sumw = waveSum(P0[lane][63]);
  float thr = M0f * sumw;

  int q = blockIdx.x * 16 + wv;
  int qi = q >> 6, qj = q & 63;
  int di = qi - lane;          // lane == point-row index
  int disq = di * di;

  // Binary search smallest k with F(k) >= thr.
  int lo = -1, hi = KMAXD2;
  float Flo = 0.f;
  while (hi - lo > 1) {
    int mid = (lo + hi) >> 1;
    float s0 = 0.f;
    int rem = mid - disq;
    if (rem >= 0) {
      int r = isqrt_i(rem);
      int l0 = qj - r; l0 = l0 < 0 ? 0 : l0;
      int h0 = qj + r; h0 = h0 > 63 ? 63 : h0;
      s0 = P0[lane][h0] - (l0 > 0 ? P0[lane][l0 - 1] : 0.f);
    }
    float F = waveSum(s0);
    if (F >= thr) hi = mid; else { lo = mid; Flo = F; }
  }
  int kstar = hi;
  float Fm = Flo;

  // G = sum of w*k over k <= kstar-1
  float g = 0.f;
  {
    int rem = (kstar - 1) - disq;
    if (rem >= 0) {
      int r = isqrt_i(rem);
      int l0 = qj - r; l0 = l0 < 0 ? 0 : l0;
      int h0 = qj + r; h0 = h0 > 63 ? 63 : h0;
      float S0 = P0[lane][h0] - (l0 > 0 ? P0[lane][l0 - 1] : 0.f);
      float S1 = P1[lane][h0] - (l0 > 0 ? P1[lane][l0 - 1] : 0.f);
      float S2 = P2[lane][h0] - (l0 > 0 ? P2[lane][l0 - 1] : 0.f);
      float fq = (float)qj;
      g = (float)disq * S0 + fq * fq * S0 - 2.f * fq * S1 + S2;
    }
  }
  float G = waveSum(g);
  float val = (G + (thr - Fm) * (float)kstar) / thr;
  val = val < 0.f ? 0.f : val;
  float res = (224.f / 63.f) * sqrtf(val);
  if (lane == 0) fout[b * NPTS + q] = res;
}

// ---------------- Kernel 2: PH0 (basin contraction) + landscape + MLP, fused ----------------
__device__ inline void bitonic_sort(u64* a, int npad, int tid) {
  for (int k = 2; k <= npad; k <<= 1) {
    for (int j = k >> 1; j > 0; j >>= 1) {
      for (int i = tid; i < npad; i += 1024) {
        int ixj = i ^ j;
        if (ixj > i) {
          u64 x = a[i], y = a[ixj];
          bool up = ((i & k) == 0);
          if (up ? (x > y) : (x < y)) { a[i] = y; a[ixj] = x; }
        }
      }
      __syncthreads();
    }
  }
}

__global__ __launch_bounds__(1024) void ph_kernel(const float* __restrict__ fin,
                                                  const float* __restrict__ Wg,
                                                  const float* __restrict__ bg,
                                                  const float* __restrict__ Wfc,
                                                  const float* __restrict__ bfc,
                                                  float* __restrict__ out) {
  __shared__ float sf[NPTS];
  __shared__ __align__(16) int srep[NPTS];    // later aliased: unsigned ptable[4096]
  __shared__ __align__(16) int sbasin[NPTS];  // later aliased: u64 slist2[LISTCAP]
  __shared__ float smu[128];
  __shared__ int sminv[128];
  __shared__ float2 spairs[PAIRCAP];
  __shared__ float sland[50];
  __shared__ float sx[50];
  __shared__ int c_m, c_l2, c_np;
  __shared__ unsigned fminb, fmaxb;

  int b = blockIdx.x;
  int tid = threadIdx.x;
  if (tid == 0) { c_m = 0; c_l2 = 0; c_np = 0; fminb = 0x7f800000u; fmaxb = 0u; }
  if (tid < 128) { smu[tid] = 3.0e38f; sminv[tid] = tid; }
  __syncthreads();

  for (int v = tid; v < NPTS; v += 1024) {
    float x = fin[b * NPTS + v];
    sf[v] = x;
    atomicMin(&fminb, __float_as_uint(x));  // f >= 0: uint order == float order
    atomicMax(&fmaxb, __float_as_uint(x));
  }
  __syncthreads();

  // steepest-descent pointers (lexicographic (f, index) tie-break)
  for (int v = tid; v < NPTS; v += 1024) {
    int vi = v >> 6, vj = v & 63;
    float bf = sf[v]; int bi = v;
    if (vj > 0)  { float fn = sf[v - 1];  int n = v - 1;  if (fn < bf || (fn == bf && n < bi)) { bf = fn; bi = n; } }
    if (vj < 63) { float fn = sf[v + 1];  int n = v + 1;  if (fn < bf || (fn == bf && n < bi)) { bf = fn; bi = n; } }
    if (vi > 0)  { float fn = sf[v - 64]; int n = v - 64; if (fn < bf || (fn == bf && n < bi)) { bf = fn; bi = n; } }
    if (vi < 63) { float fn = sf[v + 64]; int n = v + 64; if (fn < bf || (fn == bf && n < bi)) { bf = fn; bi = n; } }
    srep[v] = bi;
  }
  __syncthreads();

  // pointer jumping to basin minima (2^12 >= any path length)
  for (int it = 0; it < 12; ++it) {
    for (int v = tid; v < NPTS; v += 1024) srep[v] = srep[srep[v]];
    __syncthreads();
  }

  // compact basin ids at minima
  for (int v = tid; v < NPTS; v += 1024) {
    if (srep[v] == v) {
      int id = atomicAdd(&c_m, 1);
      if (id < IDCAP) { sbasin[v] = id; smu[id] = sf[v]; sminv[id] = v; }
      else sbasin[v] = IDCAP - 1;
    }
  }
  __syncthreads();
  for (int v = tid; v < NPTS; v += 1024) {
    if (srep[v] != v) sbasin[v] = sbasin[srep[v]];
  }
  __syncthreads();   // srep dead from here

  // ---- dedup via triangular pair table (aliases srep), atomicMin on weight bits ----
  unsigned* ptable = (unsigned*)srep;
  for (int i = tid; i < 4096; i += 1024) ptable[i] = 0xFFFFFFFFu;
  __syncthreads();
  for (int e = tid; e < NEDGE; e += 1024) {
    int u, v2;
    if (e < 4032) { int i = e / 63; int j = e - i * 63; u = (i << 6) | j; v2 = u + 1; }
    else          { int e2 = e - 4032; u = e2; v2 = u + 64; }
    int bu = sbasin[u], bv = sbasin[v2];
    if (bu != bv) {
      float wgt = fmaxf(sf[u], sf[v2]);
      int a = bu < bv ? bu : bv, bb2 = bu < bv ? bv : bu;
      int t = (bb2 * (bb2 - 1)) / 2 + a;      // a < bb2 < IDCAP -> t < 4096
      atomicMin(&ptable[t], __float_as_uint(wgt));
    }
  }
  __syncthreads();   // sbasin dead from here

  // ---- compact table -> slist2 (aliases sbasin): (w<<32) | (b<<8) | a ----
  u64* slist2 = (u64*)sbasin;
  for (int t = tid; t < 4096; t += 1024) {
    unsigned wv2 = ptable[t];
    if (wv2 != 0xFFFFFFFFu) {
      int bb2 = (int)((1.0f + sqrtf(1.0f + 8.0f * (float)t)) * 0.5f);
      while (bb2 > 1 && (bb2 * (bb2 - 1)) / 2 > t) bb2--;
      while (((bb2 + 1) * bb2) / 2 <= t) bb2++;
      int aa = t - (bb2 * (bb2 - 1)) / 2;
      int slot = atomicAdd(&c_l2, 1);
      if (slot < LISTCAP) slist2[slot] = ((u64)wv2 << 32) | (unsigned)((bb2 << 8) | aa);
    }
  }
  __syncthreads();
  int n2 = c_l2; if (n2 > LISTCAP) n2 = LISTCAP;
  int npad2 = 1; while (npad2 < n2) npad2 <<= 1;
  if (n2 == 0) npad2 = 0;
  for (int i = n2 + tid; i < npad2; i += 1024) slist2[i] = ~0ull;
  __syncthreads();
  bitonic_sort(slist2, npad2, tid);  // ascending by weight (keys distinct -> deterministic)

  // ---- serial Kruskal, wave 0, ALWAYS-COMPRESSED parents in registers ----
  // invariant: p0/p1 hold the ROOT id for ids (lane) and (64+lane). find == 1 shfl.
  int lane = tid & 63;
  if (tid < 64) {
    int p0 = lane, p1 = 64 + lane;
    float mu0 = smu[lane], mu1 = smu[64 + lane];
    int rv0 = sminv[lane], rv1 = sminv[64 + lane];
    int np = 0;
    for (int base = 0; base < n2; base += 64) {
      int idx = base + lane;
      u64 ev = (idx < n2) ? slist2[idx] : ~0ull;
      int a_l = (int)(ev & 0xffull);
      int b_l = (int)((ev >> 8) & 0xffull);
      int w_l = (int)(unsigned)(ev >> 32);
      // parallel pre-filter: roots of all 64 edges concurrently (compressed => 1 hop)
      int ra_pre = (a_l < 64) ? __shfl(p0, a_l) : __shfl(p1, a_l & 63);
      int rb_pre = (b_l < 64) ? __shfl(p0, b_l) : __shfl(p1, b_l & 63);
      u64 cand = __ballot((ra_pre != rb_pre) && (idx < n2));
      while (cand) {
        int s = __builtin_ctzll(cand); cand &= cand - 1;
        int a = __shfl(a_l, s), bb2 = __shfl(b_l, s);
        unsigned wb = (unsigned)__shfl(w_l, s);
        int ra = (a < 64) ? __shfl(p0, a) : __shfl(p1, a & 63);
        int rb = (bb2 < 64) ? __shfl(p0, bb2) : __shfl(p1, bb2 & 63);
        if (ra == rb) continue;
        float mua = (ra < 64) ? __shfl(mu0, ra) : __shfl(mu1, ra & 63);
        float mub = (rb < 64) ? __shfl(mu0, rb) : __shfl(mu1, rb & 63);
        int rva = (ra < 64) ? __shfl(rv0, ra) : __shfl(rv1, ra & 63);
        int rvb = (rb < 64) ? __shfl(rv0, rb) : __shfl(rv1, rb & 63);
        bool aeld = (mua < mub) || (mua == mub && rva <= rvb);
        int eld = aeld ? ra : rb, yng = aeld ? rb : ra;
        float byoung = aeld ? mub : mua;
        // recompress: every id whose root was yng now roots at eld (pure VALU, no shfl)
        p0 = (p0 == yng) ? eld : p0;
        p1 = (p1 == yng) ? eld : p1;
        if (lane == 0 && np < PAIRCAP - 1) spairs[np] = make_float2(byoung, __uint_as_float(wb));
        np++;
      }
    }
    if (np > PAIRCAP - 1) np = PAIRCAP - 1;
    if (lane == 0) {
      spairs[np] = make_float2(__uint_as_float(fminb), __uint_as_float(fmaxb));  // essential pair
      c_np = np + 1;
    }
  }
  __syncthreads();

  // ---- landscape (top-2 triangles at 25 t's) ----
  int totp = c_np;
  if (tid < 25) {
    float tv = 1.875f * (float)tid;  // linspace(0,45,25)
    float top1 = 0.f, top2 = 0.f;
    for (int i = 0; i < totp; ++i) {
      float2 p = spairs[i];
      float tri = fminf(tv - p.x, p.y - tv);
      tri = fmaxf(tri, 0.f);
      if (tri > top1) { top2 = top1; top1 = tri; }
      else if (tri > top2) top2 = tri;
    }
    sland[tid] = top1;
    sland[25 + tid] = top2;
  }
  __syncthreads();

  // ---- x = land @ Wg.T + bg ----
  if (tid < 50) {
    float acc = bg[tid];
    for (int k = 0; k < 50; ++k) acc += sland[k] * Wg[tid * 50 + k];
    sx[tid] = acc;
  }
  __syncthreads();

  // ---- outputs: out[0:20] per-batch rows; out[20:70] signal via atomicAdd (zeroed by host memset) ----
  if (tid < 50) atomicAdd(&out[20 + tid], fabsf(sx[tid]));
  if (tid >= 64 && tid < 74) {
    int c = tid - 64;
    float acc = bfc[c];
    for (int o = 0; o < 50; ++o) acc += fmaxf(sx[o], 0.f) * Wfc[c * 50 + o];
    out[b * 10 + c] = acc;
  }
}

extern "C" void kernel_launch(void* const* d_in, const int* in_sizes, int n_in,
                              void* d_out, int out_size, void* d_ws, size_t ws_size,
                              hipStream_t stream) {
  (void)in_sizes; (void)n_in; (void)out_size; (void)ws_size;
  const float* input = (const float*)d_in[0];
  const float* Wg  = (const float*)d_in[1];
  const float* bg  = (const float*)d_in[2];
  const float* Wfc = (const float*)d_in[3];
  const float* bfc = (const float*)d_in[4];
  float* out = (float*)d_out;

  float* f_ws = (float*)d_ws;  // 2*4096 f32

  hipMemsetAsync(out, 0, 70 * sizeof(float), stream);  // signal accumulated via atomicAdd
  dtm_kernel<<<dim3(256, 2), 1024, 0, stream>>>(input, f_ws);
  ph_kernel<<<dim3(2), 1024, 0, stream>>>(f_ws, Wg, bg, Wfc, bfc, out);
}

// Round 7
// 87.836 us; speedup vs baseline: 1.8099x; 1.2737x over previous
//
#include <hip/hip_runtime.h>

#define NPTS 4096
#define NEDGE 8064
#define M0f 0.05f
#define KMAXD2 7938
#define IDCAP 90          // basin-id clamp; triangular pair table needs IDCAP*(IDCAP-1)/2 <= 4096
#define LISTCAP 2048
#define PAIRCAP 160

typedef unsigned long long u64;

__device__ inline float waveSum(float x) {
  for (int m = 32; m >= 1; m >>= 1) x += __shfl_xor(x, m);
  return x;
}

__device__ inline int isqrt_i(int x) {  // exact floor sqrt for 0 <= x < 2^20
  int r = (int)sqrtf((float)x);
  if ((r + 1) * (r + 1) <= x) r++;
  else if (r * r > x) r--;
  return r;
}

// ---------------- Kernel 1: DTM ----------------
// grid (256, B), block 1024 (16 waves). One wave per query point.
__global__ __launch_bounds__(1024) void dtm_kernel(const float* __restrict__ win,
                                                   float* __restrict__ fout) {
  __shared__ float P0[64][65];
  __shared__ float P1[64][65];
  __shared__ float P2[64][65];
  int b = blockIdx.y;
  const float* w = win + b * NPTS;
  int tid = threadIdx.x, lane = tid & 63, wv = tid >> 6;

  // Build per-row inclusive prefix sums of w, w*j, w*j^2 (query-independent).
  for (int rr = 0; rr < 4; ++rr) {
    int r = (wv << 2) | rr;
    float x0 = w[(r << 6) | lane];
    float fl = (float)lane;
    float x1 = x0 * fl, x2 = x1 * fl;
    for (int d = 1; d < 64; d <<= 1) {
      float t0 = __shfl_up(x0, d);
      float t1 = __shfl_up(x1, d);
      float t2 = __shfl_up(x2, d);
      if (lane >= d) { x0 += t0; x1 += t1; x2 += t2; }
    }
    P0[r][lane] = x0; P1[r][lane] = x1; P2[r][lane] = x2;
  }
  __syncthreads();

  float sumw = waveSum(P0[lane][63]);
  float thr = M0f * sumw;

  int q = blockIdx.x * 16 + wv;
  int qi = q >> 6, qj = q & 63;
  int di = qi - lane;          // lane == point-row index
  int disq = di * di;

  // Binary search smallest k with F(k) >= thr.
  int lo = -1, hi = KMAXD2;
  float Flo = 0.f;
  while (hi - lo > 1) {
    int mid = (lo + hi) >> 1;
    float s0 = 0.f;
    int rem = mid - disq;
    if (rem >= 0) {
      int r = isqrt_i(rem);
      int l0 = qj - r; l0 = l0 < 0 ? 0 : l0;
      int h0 = qj + r; h0 = h0 > 63 ? 63 : h0;
      s0 = P0[lane][h0] - (l0 > 0 ? P0[lane][l0 - 1] : 0.f);
    }
    float F = waveSum(s0);
    if (F >= thr) hi = mid; else { lo = mid; Flo = F; }
  }
  int kstar = hi;
  float Fm = Flo;

  // G = sum of w*k over k <= kstar-1
  float g = 0.f;
  {
    int rem = (kstar - 1) - disq;
    if (rem >= 0) {
      int r = isqrt_i(rem);
      int l0 = qj - r; l0 = l0 < 0 ? 0 : l0;
      int h0 = qj + r; h0 = h0 > 63 ? 63 : h0;
      float S0 = P0[lane][h0] - (l0 > 0 ? P0[lane][l0 - 1] : 0.f);
      float S1 = P1[lane][h0] - (l0 > 0 ? P1[lane][l0 - 1] : 0.f);
      float S2 = P2[lane][h0] - (l0 > 0 ? P2[lane][l0 - 1] : 0.f);
      float fq = (float)qj;
      g = (float)disq * S0 + fq * fq * S0 - 2.f * fq * S1 + S2;
    }
  }
  float G = waveSum(g);
  float val = (G + (thr - Fm) * (float)kstar) / thr;
  val = val < 0.f ? 0.f : val;
  float res = (224.f / 63.f) * sqrtf(val);
  if (lane == 0) fout[b * NPTS + q] = res;
}

// ---------------- Kernel 2: PH0 (basin contraction) + landscape + MLP, fused ----------------
__device__ inline void bitonic_sort(u64* a, int npad, int tid) {
  for (int k = 2; k <= npad; k <<= 1) {
    for (int j = k >> 1; j > 0; j >>= 1) {
      for (int i = tid; i < npad; i += 1024) {
        int ixj = i ^ j;
        if (ixj > i) {
          u64 x = a[i], y = a[ixj];
          bool up = ((i & k) == 0);
          if (up ? (x > y) : (x < y)) { a[i] = y; a[ixj] = x; }
        }
      }
      __syncthreads();
    }
  }
}

__global__ __launch_bounds__(1024) void ph_kernel(const float* __restrict__ fin,
                                                  const float* __restrict__ Wg,
                                                  const float* __restrict__ bg,
                                                  const float* __restrict__ Wfc,
                                                  const float* __restrict__ bfc,
                                                  float* __restrict__ out) {
  __shared__ float sf[NPTS];
  __shared__ __align__(16) int srep[NPTS];    // later aliased: unsigned ptable[4096]
  __shared__ __align__(16) int sbasin[NPTS];  // later aliased: u64 slist2[LISTCAP]
  __shared__ float smu[128];
  __shared__ int sminv[128];
  __shared__ float2 spairs[PAIRCAP];
  __shared__ float sland[50];
  __shared__ float sx[50];
  __shared__ int c_m, c_l2, c_np;
  __shared__ unsigned fminb, fmaxb;

  int b = blockIdx.x;
  int tid = threadIdx.x;
  if (tid == 0) { c_m = 0; c_l2 = 0; c_np = 0; fminb = 0x7f800000u; fmaxb = 0u; }
  if (tid < 128) { smu[tid] = 3.0e38f; sminv[tid] = tid; }
  __syncthreads();

  // load f; per-wave min/max reduction, ONE LDS atomic per wave (not per thread)
  {
    float lmin = 3.0e38f, lmax = 0.f;
    for (int v = tid; v < NPTS; v += 1024) {
      float x = fin[b * NPTS + v];
      sf[v] = x;
      lmin = fminf(lmin, x);
      lmax = fmaxf(lmax, x);
    }
    for (int m = 32; m >= 1; m >>= 1) {
      lmin = fminf(lmin, __shfl_xor(lmin, m));
      lmax = fmaxf(lmax, __shfl_xor(lmax, m));
    }
    if ((tid & 63) == 0) {
      atomicMin(&fminb, __float_as_uint(lmin));  // f >= 0: uint order == float order
      atomicMax(&fmaxb, __float_as_uint(lmax));
    }
  }
  __syncthreads();

  // steepest-descent pointers (lexicographic (f, index) tie-break)
  for (int v = tid; v < NPTS; v += 1024) {
    int vi = v >> 6, vj = v & 63;
    float bf = sf[v]; int bi = v;
    if (vj > 0)  { float fn = sf[v - 1];  int n = v - 1;  if (fn < bf || (fn == bf && n < bi)) { bf = fn; bi = n; } }
    if (vj < 63) { float fn = sf[v + 1];  int n = v + 1;  if (fn < bf || (fn == bf && n < bi)) { bf = fn; bi = n; } }
    if (vi > 0)  { float fn = sf[v - 64]; int n = v - 64; if (fn < bf || (fn == bf && n < bi)) { bf = fn; bi = n; } }
    if (vi < 63) { float fn = sf[v + 64]; int n = v + 64; if (fn < bf || (fn == bf && n < bi)) { bf = fn; bi = n; } }
    srep[v] = bi;
  }
  __syncthreads();

  // pointer jumping to basin minima (2^12 >= any path length)
  for (int it = 0; it < 12; ++it) {
    for (int v = tid; v < NPTS; v += 1024) srep[v] = srep[srep[v]];
    __syncthreads();
  }

  // compact basin ids at minima
  for (int v = tid; v < NPTS; v += 1024) {
    if (srep[v] == v) {
      int id = atomicAdd(&c_m, 1);
      if (id < IDCAP) { sbasin[v] = id; smu[id] = sf[v]; sminv[id] = v; }
      else sbasin[v] = IDCAP - 1;
    }
  }
  __syncthreads();
  for (int v = tid; v < NPTS; v += 1024) {
    if (srep[v] != v) sbasin[v] = sbasin[srep[v]];
  }
  __syncthreads();   // srep dead from here

  // ---- dedup via triangular pair table (aliases srep), atomicMin on weight bits ----
  unsigned* ptable = (unsigned*)srep;
  for (int i = tid; i < 4096; i += 1024) ptable[i] = 0xFFFFFFFFu;
  __syncthreads();
  for (int e = tid; e < NEDGE; e += 1024) {
    int u, v2;
    if (e < 4032) { int i = e / 63; int j = e - i * 63; u = (i << 6) | j; v2 = u + 1; }
    else          { int e2 = e - 4032; u = e2; v2 = u + 64; }
    int bu = sbasin[u], bv = sbasin[v2];
    if (bu != bv) {
      float wgt = fmaxf(sf[u], sf[v2]);
      int a = bu < bv ? bu : bv, bb2 = bu < bv ? bv : bu;
      int t = (bb2 * (bb2 - 1)) / 2 + a;      // a < bb2 < IDCAP -> t < 4096
      atomicMin(&ptable[t], __float_as_uint(wgt));
    }
  }
  __syncthreads();   // sbasin dead from here

  // ---- compact table -> slist2 (aliases sbasin): (w<<32) | (b<<8) | a ----
  u64* slist2 = (u64*)sbasin;
  for (int t = tid; t < 4096; t += 1024) {
    unsigned wv2 = ptable[t];
    if (wv2 != 0xFFFFFFFFu) {
      int bb2 = (int)((1.0f + sqrtf(1.0f + 8.0f * (float)t)) * 0.5f);
      while (bb2 > 1 && (bb2 * (bb2 - 1)) / 2 > t) bb2--;
      while (((bb2 + 1) * bb2) / 2 <= t) bb2++;
      int aa = t - (bb2 * (bb2 - 1)) / 2;
      int slot = atomicAdd(&c_l2, 1);
      if (slot < LISTCAP) slist2[slot] = ((u64)wv2 << 32) | (unsigned)((bb2 << 8) | aa);
    }
  }
  __syncthreads();
  int n2 = c_l2; if (n2 > LISTCAP) n2 = LISTCAP;
  int npad2 = 1; while (npad2 < n2) npad2 <<= 1;
  if (n2 == 0) npad2 = 0;
  for (int i = n2 + tid; i < npad2; i += 1024) slist2[i] = ~0ull;
  __syncthreads();
  bitonic_sort(slist2, npad2, tid);  // ascending by weight (keys distinct -> deterministic)

  // ---- serial Kruskal, wave 0, ALWAYS-COMPRESSED parents in registers ----
  // invariant: p0/p1 hold the ROOT id for ids (lane) and (64+lane). find == 1 shfl.
  int lane = tid & 63;
  if (tid < 64) {
    int p0 = lane, p1 = 64 + lane;
    float mu0 = smu[lane], mu1 = smu[64 + lane];
    int rv0 = sminv[lane], rv1 = sminv[64 + lane];
    int np = 0;
    for (int base = 0; base < n2; base += 64) {
      int idx = base + lane;
      u64 ev = (idx < n2) ? slist2[idx] : ~0ull;
      int a_l = (int)(ev & 0xffull);
      int b_l = (int)((ev >> 8) & 0xffull);
      int w_l = (int)(unsigned)(ev >> 32);
      // parallel pre-filter: roots of all 64 edges concurrently (compressed => 1 hop)
      int ra_pre = (a_l < 64) ? __shfl(p0, a_l) : __shfl(p1, a_l & 63);
      int rb_pre = (b_l < 64) ? __shfl(p0, b_l) : __shfl(p1, b_l & 63);
      u64 cand = __ballot((ra_pre != rb_pre) && (idx < n2));
      while (cand) {
        int s = __builtin_ctzll(cand); cand &= cand - 1;
        int a = __shfl(a_l, s), bb2 = __shfl(b_l, s);
        unsigned wb = (unsigned)__shfl(w_l, s);
        int ra = (a < 64) ? __shfl(p0, a) : __shfl(p1, a & 63);
        int rb = (bb2 < 64) ? __shfl(p0, bb2) : __shfl(p1, bb2 & 63);
        if (ra == rb) continue;
        float mua = (ra < 64) ? __shfl(mu0, ra) : __shfl(mu1, ra & 63);
        float mub = (rb < 64) ? __shfl(mu0, rb) : __shfl(mu1, rb & 63);
        int rva = (ra < 64) ? __shfl(rv0, ra) : __shfl(rv1, ra & 63);
        int rvb = (rb < 64) ? __shfl(rv0, rb) : __shfl(rv1, rb & 63);
        bool aeld = (mua < mub) || (mua == mub && rva <= rvb);
        int eld = aeld ? ra : rb, yng = aeld ? rb : ra;
        float byoung = aeld ? mub : mua;
        // recompress: every id whose root was yng now roots at eld (pure VALU, no shfl)
        p0 = (p0 == yng) ? eld : p0;
        p1 = (p1 == yng) ? eld : p1;
        if (lane == 0 && np < PAIRCAP - 1) spairs[np] = make_float2(byoung, __uint_as_float(wb));
        np++;
      }
    }
    if (np > PAIRCAP - 1) np = PAIRCAP - 1;
    if (lane == 0) {
      spairs[np] = make_float2(__uint_as_float(fminb), __uint_as_float(fmaxb));  // essential pair
      c_np = np + 1;
    }
  }
  __syncthreads();

  // ---- landscape (top-2 triangles at 25 t's) ----
  int totp = c_np;
  if (tid < 25) {
    float tv = 1.875f * (float)tid;  // linspace(0,45,25)
    float top1 = 0.f, top2 = 0.f;
    for (int i = 0; i < totp; ++i) {
      float2 p = spairs[i];
      float tri = fminf(tv - p.x, p.y - tv);
      tri = fmaxf(tri, 0.f);
      if (tri > top1) { top2 = top1; top1 = tri; }
      else if (tri > top2) top2 = tri;
    }
    sland[tid] = top1;
    sland[25 + tid] = top2;
  }
  __syncthreads();

  // ---- x = land @ Wg.T + bg ----
  if (tid < 50) {
    float acc = bg[tid];
    for (int k = 0; k < 50; ++k) acc += sland[k] * Wg[tid * 50 + k];
    sx[tid] = acc;
  }
  __syncthreads();

  // ---- outputs: out[0:20] per-batch rows; out[20:70] signal via atomicAdd (zeroed by host memset) ----
  if (tid < 50) atomicAdd(&out[20 + tid], fabsf(sx[tid]));
  if (tid >= 64 && tid < 74) {
    int c = tid - 64;
    float acc = bfc[c];
    for (int o = 0; o < 50; ++o) acc += fmaxf(sx[o], 0.f) * Wfc[c * 50 + o];
    out[b * 10 + c] = acc;
  }
}

extern "C" void kernel_launch(void* const* d_in, const int* in_sizes, int n_in,
                              void* d_out, int out_size, void* d_ws, size_t ws_size,
                              hipStream_t stream) {
  (void)in_sizes; (void)n_in; (void)out_size; (void)ws_size;
  const float* input = (const float*)d_in[0];
  const float* Wg  = (const float*)d_in[1];
  const float* bg  = (const float*)d_in[2];
  const float* Wfc = (const float*)d_in[3];
  const float* bfc = (const float*)d_in[4];
  float* out = (float*)d_out;

  float* f_ws = (float*)d_ws;  // 2*4096 f32

  hipMemsetAsync(out, 0, 70 * sizeof(float), stream);  // signal accumulated via atomicAdd
  dtm_kernel<<<dim3(256, 2), 1024, 0, stream>>>(input, f_ws);
  ph_kernel<<<dim3(2), 1024, 0, stream>>>(f_ws, Wg, bg, Wfc, bfc, out);
}

// Round 9
// 86.585 us; speedup vs baseline: 1.8361x; 1.0144x over previous
//
#include <hip/hip_runtime.h>

#define NPTS 4096
#define NEDGE 8064
#define M0f 0.05f
#define KMAXD2 7938
#define IDCAP 90          // basin-id clamp; triangular pair table needs IDCAP*(IDCAP-1)/2 <= 4096
#define SORTCAP 512       // in-wave sort capacity (8 regs/lane x 64 lanes)
#define PAIRCAP 160

typedef unsigned long long u64;

__device__ inline float waveSum(float x) {
  for (int m = 32; m >= 1; m >>= 1) x += __shfl_xor(x, m);
  return x;
}

__device__ inline int isqrt_i(int x) {  // exact floor sqrt for 0 <= x < 2^20
  int r = (int)sqrtf((float)x);
  if ((r + 1) * (r + 1) <= x) r++;
  else if (r * r > x) r--;
  return r;
}

__device__ inline u64 shfl64(u64 x, int src) {  // broadcast
  int lo = __shfl((int)(unsigned)(x & 0xffffffffull), src);
  int hi = __shfl((int)(unsigned)(x >> 32), src);
  return ((u64)(unsigned)hi << 32) | (u64)(unsigned)lo;
}

__device__ inline u64 shfl_xor64(u64 x, int m) {
  int lo = __shfl_xor((int)(unsigned)(x & 0xffffffffull), m);
  int hi = __shfl_xor((int)(unsigned)(x >> 32), m);
  return ((u64)(unsigned)hi << 32) | (u64)(unsigned)lo;
}

// ---------------- Kernel 1: DTM ----------------
// grid (256, B), block 1024 (16 waves). One wave per query point.
__global__ __launch_bounds__(1024) void dtm_kernel(const float* __restrict__ win,
                                                   float* __restrict__ fout) {
  __shared__ float P0[64][65];
  __shared__ float P1[64][65];
  __shared__ float P2[64][65];
  int b = blockIdx.y;
  const float* w = win + b * NPTS;
  int tid = threadIdx.x, lane = tid & 63, wv = tid >> 6;

  // Build per-row inclusive prefix sums of w, w*j, w*j^2 (query-independent).
  for (int rr = 0; rr < 4; ++rr) {
    int r = (wv << 2) | rr;
    float x0 = w[(r << 6) | lane];
    float fl = (float)lane;
    float x1 = x0 * fl, x2 = x1 * fl;
    for (int d = 1; d < 64; d <<= 1) {
      float t0 = __shfl_up(x0, d);
      float t1 = __shfl_up(x1, d);
      float t2 = __shfl_up(x2, d);
      if (lane >= d) { x0 += t0; x1 += t1; x2 += t2; }
    }
    P0[r][lane] = x0; P1[r][lane] = x1; P2[r][lane] = x2;
  }
  __syncthreads();

  float sumw = waveSum(P0[lane][63]);
  float thr = M0f * sumw;

  int q = blockIdx.x * 16 + wv;
  int qi = q >> 6, qj = q & 63;
  int di = qi - lane;          // lane == point-row index
  int disq = di * di;

  auto evalF = [&](int K) -> float {
    float s0 = 0.f;
    int rem = K - disq;
    if (rem >= 0) {
      int r = isqrt_i(rem);
      int l0 = qj - r; l0 = l0 < 0 ? 0 : l0;
      int h0 = qj + r; h0 = h0 > 63 ? 63 : h0;
      s0 = P0[lane][h0] - (l0 > 0 ? P0[lane][l0 - 1] : 0.f);
    }
    return waveSum(s0);
  };

  // Galloping bracket (k* is typically <= 260 for this data), then binary search.
  int lo = -1, hi = 256;
  float Flo = 0.f;
  for (;;) {
    float F = evalF(hi);
    if (F >= thr || hi == KMAXD2) break;
    lo = hi; Flo = F;
    hi = (hi == 256) ? 1024 : KMAXD2;
  }
  while (hi - lo > 1) {
    int mid = (lo + hi) >> 1;
    float F = evalF(mid);
    if (F >= thr) hi = mid; else { lo = mid; Flo = F; }
  }
  int kstar = hi;
  float Fm = Flo;

  // G = sum of w*k over k <= kstar-1
  float g = 0.f;
  {
    int rem = (kstar - 1) - disq;
    if (rem >= 0) {
      int r = isqrt_i(rem);
      int l0 = qj - r; l0 = l0 < 0 ? 0 : l0;
      int h0 = qj + r; h0 = h0 > 63 ? 63 : h0;
      float S0 = P0[lane][h0] - (l0 > 0 ? P0[lane][l0 - 1] : 0.f);
      float S1 = P1[lane][h0] - (l0 > 0 ? P1[lane][l0 - 1] : 0.f);
      float S2 = P2[lane][h0] - (l0 > 0 ? P2[lane][l0 - 1] : 0.f);
      float fq = (float)qj;
      g = (float)disq * S0 + fq * fq * S0 - 2.f * fq * S1 + S2;
    }
  }
  float G = waveSum(g);
  float val = (G + (thr - Fm) * (float)kstar) / thr;
  val = val < 0.f ? 0.f : val;
  float res = (224.f / 63.f) * sqrtf(val);
  if (lane == 0) fout[b * NPTS + q] = res;
}

// ---------------- in-wave bitonic compare-exchange macros (512 elems, 8 u64/lane) ----------------
// element index i = R*64 + lane. CXL: cross-lane partner (j<64). CXR: cross-register (j>=64).
#define CXL(R, J, K) { \
  u64 vo = shfl_xor64(e##R, J); \
  bool up = (((((R) * 64) & (K)) | (lane & (K))) == 0); \
  bool lower = ((lane & (J)) == 0); \
  bool kmin = (lower == up); \
  u64 mn = (e##R < vo) ? e##R : vo; \
  u64 mx = (e##R < vo) ? vo : e##R; \
  e##R = kmin ? mn : mx; }
#define ALL8(J, K) CXL(0,J,K) CXL(1,J,K) CXL(2,J,K) CXL(3,J,K) CXL(4,J,K) CXL(5,J,K) CXL(6,J,K) CXL(7,J,K)
#define CXR(RA, RB, K) { \
  const bool up = ((((RA) * 64) & (K)) == 0); \
  u64 va = e##RA, vb = e##RB; \
  u64 mn = (va < vb) ? va : vb; \
  u64 mx = (va < vb) ? vb : va; \
  e##RA = up ? mn : mx; e##RB = up ? mx : mn; }

// ---------------- Kernel 2: PH0 (basin contraction) + landscape + MLP, fused ----------------
__global__ __launch_bounds__(1024) void ph_kernel(const float* __restrict__ fin,
                                                  const float* __restrict__ Wg,
                                                  const float* __restrict__ bg,
                                                  const float* __restrict__ Wfc,
                                                  const float* __restrict__ bfc,
                                                  float* __restrict__ out) {
  __shared__ float sf[NPTS];
  __shared__ __align__(16) int srep[NPTS];    // later aliased: unsigned ptable[4096]
  __shared__ __align__(16) int sbasin[NPTS];  // later aliased: u64 slist2[SORTCAP]
  __shared__ float smu[128];
  __shared__ int sminv[128];
  __shared__ float2 spairs[PAIRCAP];
  __shared__ float sland[50];
  __shared__ float sx[50];
  __shared__ float sWg[2500];
  __shared__ float sbg[50];
  __shared__ float sWfc[500];
  __shared__ float sbfc[10];
  __shared__ int c_m, c_l2, c_np;
  __shared__ unsigned fminb, fmaxb;

  int b = blockIdx.x;
  int tid = threadIdx.x;
  if (tid == 0) { c_m = 0; c_l2 = 0; c_np = 0; fminb = 0x7f800000u; fmaxb = 0u; }
  if (tid < 128) { smu[tid] = 3.0e38f; sminv[tid] = tid; }

  // prefetch MLP weights into LDS (latency absorbed by the first barrier drains)
  for (int i = tid; i < 2500; i += 1024) sWg[i] = Wg[i];
  for (int i = tid; i < 500; i += 1024) sWfc[i] = Wfc[i];
  if (tid < 50) sbg[tid] = bg[tid];
  if (tid < 10) sbfc[tid] = bfc[tid];

  // load f; per-wave min/max reduction, ONE LDS atomic per wave
  {
    float lmin = 3.0e38f, lmax = 0.f;
    for (int v = tid; v < NPTS; v += 1024) {
      float x = fin[b * NPTS + v];
      sf[v] = x;
      lmin = fminf(lmin, x);
      lmax = fmaxf(lmax, x);
    }
    for (int m = 32; m >= 1; m >>= 1) {
      lmin = fminf(lmin, __shfl_xor(lmin, m));
      lmax = fmaxf(lmax, __shfl_xor(lmax, m));
    }
    if ((tid & 63) == 0) {
      atomicMin(&fminb, __float_as_uint(lmin));  // f >= 0: uint order == float order
      atomicMax(&fmaxb, __float_as_uint(lmax));
    }
  }
  __syncthreads();

  // steepest-descent pointers (lexicographic (f, index) tie-break); keep in registers too
  int preg[4];
#pragma unroll 4
  for (int s = 0; s < 4; ++s) {
    int v = tid + s * 1024;
    int vi = v >> 6, vj = v & 63;
    float bf = sf[v]; int bi = v;
    if (vj > 0)  { float fn = sf[v - 1];  int n = v - 1;  if (fn < bf || (fn == bf && n < bi)) { bf = fn; bi = n; } }
    if (vj < 63) { float fn = sf[v + 1];  int n = v + 1;  if (fn < bf || (fn == bf && n < bi)) { bf = fn; bi = n; } }
    if (vi > 0)  { float fn = sf[v - 64]; int n = v - 64; if (fn < bf || (fn == bf && n < bi)) { bf = fn; bi = n; } }
    if (vi < 63) { float fn = sf[v + 64]; int n = v + 64; if (fn < bf || (fn == bf && n < bi)) { bf = fn; bi = n; } }
    srep[v] = bi;
    preg[s] = bi;
  }
  __syncthreads();

  // pointer jumping, register-carried (1 LDS read per round; benign monotone races, >= doubling)
  for (int it = 0; it < 12; ++it) {
#pragma unroll 4
    for (int s = 0; s < 4; ++s) {
      int x = srep[preg[s]];
      srep[tid + s * 1024] = x;
      preg[s] = x;
    }
    __syncthreads();
  }

  // compact basin ids at minima
  for (int v = tid; v < NPTS; v += 1024) {
    if (srep[v] == v) {
      int id = atomicAdd(&c_m, 1);
      if (id < IDCAP) { sbasin[v] = id; smu[id] = sf[v]; sminv[id] = v; }
      else sbasin[v] = IDCAP - 1;
    }
  }
  __syncthreads();
  for (int v = tid; v < NPTS; v += 1024) {
    if (srep[v] != v) sbasin[v] = sbasin[srep[v]];
  }
  __syncthreads();   // srep dead from here

  // ---- dedup via triangular pair table (aliases srep), atomicMin on weight bits ----
  unsigned* ptable = (unsigned*)srep;
  for (int i = tid; i < 4096; i += 1024) ptable[i] = 0xFFFFFFFFu;
  __syncthreads();
  for (int e = tid; e < NEDGE; e += 1024) {
    int u, v2;
    if (e < 4032) { int i = e / 63; int j = e - i * 63; u = (i << 6) | j; v2 = u + 1; }
    else          { int e2 = e - 4032; u = e2; v2 = u + 64; }
    int bu = sbasin[u], bv = sbasin[v2];
    if (bu != bv) {
      float wgt = fmaxf(sf[u], sf[v2]);
      int a = bu < bv ? bu : bv, bb2 = bu < bv ? bv : bu;
      int t = (bb2 * (bb2 - 1)) / 2 + a;      // a < bb2 < IDCAP -> t < 4096
      atomicMin(&ptable[t], __float_as_uint(wgt));
    }
  }
  __syncthreads();   // sbasin dead from here

  // ---- compact table -> slist2 (aliases sbasin): (w<<32) | (b<<8) | a ----
  u64* slist2 = (u64*)sbasin;
  for (int t = tid; t < 4096; t += 1024) {
    unsigned wv2 = ptable[t];
    if (wv2 != 0xFFFFFFFFu) {
      int bb2 = (int)((1.0f + sqrtf(1.0f + 8.0f * (float)t)) * 0.5f);
      while (bb2 > 1 && (bb2 * (bb2 - 1)) / 2 > t) bb2--;
      while (((bb2 + 1) * bb2) / 2 <= t) bb2++;
      int aa = t - (bb2 * (bb2 - 1)) / 2;
      int slot = atomicAdd(&c_l2, 1);
      if (slot < SORTCAP) slist2[slot] = ((u64)wv2 << 32) | (unsigned)((bb2 << 8) | aa);
    }
  }
  __syncthreads();
  int n2 = c_l2; if (n2 > SORTCAP) n2 = SORTCAP;
  for (int i = n2 + tid; i < SORTCAP; i += 1024) slist2[i] = ~0ull;
  __syncthreads();

  // ---- wave 0: in-register bitonic sort (512 elems, zero barriers) + compressed Kruskal ----
  int lane = tid & 63;
  if (tid < 64) {
    u64 e0 = slist2[lane],        e1 = slist2[64 + lane],  e2 = slist2[128 + lane], e3 = slist2[192 + lane];
    u64 e4 = slist2[256 + lane],  e5 = slist2[320 + lane], e6 = slist2[384 + lane], e7 = slist2[448 + lane];
    // bitonic network N=512, element i = R*64 + lane, ascending
    ALL8(1,2)
    ALL8(2,4) ALL8(1,4)
    ALL8(4,8) ALL8(2,8) ALL8(1,8)
    ALL8(8,16) ALL8(4,16) ALL8(2,16) ALL8(1,16)
    ALL8(16,32) ALL8(8,32) ALL8(4,32) ALL8(2,32) ALL8(1,32)
    ALL8(32,64) ALL8(16,64) ALL8(8,64) ALL8(4,64) ALL8(2,64) ALL8(1,64)
    CXR(0,1,128) CXR(2,3,128) CXR(4,5,128) CXR(6,7,128)
    ALL8(32,128) ALL8(16,128) ALL8(8,128) ALL8(4,128) ALL8(2,128) ALL8(1,128)
    CXR(0,2,256) CXR(1,3,256) CXR(4,6,256) CXR(5,7,256)
    CXR(0,1,256) CXR(2,3,256) CXR(4,5,256) CXR(6,7,256)
    ALL8(32,256) ALL8(16,256) ALL8(8,256) ALL8(4,256) ALL8(2,256) ALL8(1,256)
    CXR(0,4,512) CXR(1,5,512) CXR(2,6,512) CXR(3,7,512)
    CXR(0,2,512) CXR(1,3,512) CXR(4,6,512) CXR(5,7,512)
    CXR(0,1,512) CXR(2,3,512) CXR(4,5,512) CXR(6,7,512)
    ALL8(32,512) ALL8(16,512) ALL8(8,512) ALL8(4,512) ALL8(2,512) ALL8(1,512)

    // Kruskal with always-compressed parents (p0/p1 hold ROOT id; find == 1 shfl)
    int p0 = lane, p1 = 64 + lane;
    float mu0 = smu[lane], mu1 = smu[64 + lane];
    int rv0 = sminv[lane], rv1 = sminv[64 + lane];
    int np = 0;
#define KBATCH(R) { \
      u64 ev = e##R; \
      bool valid = (ev != ~0ull); \
      int a_l = (int)(ev & 0xffull); \
      int b_l = (int)((ev >> 8) & 0xffull); \
      int w_l = (int)(unsigned)(ev >> 32); \
      int ra_pre = (a_l < 64) ? __shfl(p0, a_l) : __shfl(p1, a_l & 63); \
      int rb_pre = (b_l < 64) ? __shfl(p0, b_l) : __shfl(p1, b_l & 63); \
      u64 cand = __ballot(valid && (ra_pre != rb_pre)); \
      while (cand) { \
        int s = __builtin_ctzll(cand); cand &= cand - 1; \
        int a = __shfl(a_l, s), bb2 = __shfl(b_l, s); \
        unsigned wb = (unsigned)__shfl(w_l, s); \
        int ra = (a < 64) ? __shfl(p0, a) : __shfl(p1, a & 63); \
        int rb = (bb2 < 64) ? __shfl(p0, bb2) : __shfl(p1, bb2 & 63); \
        if (ra == rb) continue; \
        float mua = (ra < 64) ? __shfl(mu0, ra) : __shfl(mu1, ra & 63); \
        float mub = (rb < 64) ? __shfl(mu0, rb) : __shfl(mu1, rb & 63); \
        int rva = (ra < 64) ? __shfl(rv0, ra) : __shfl(rv1, ra & 63); \
        int rvb = (rb < 64) ? __shfl(rv0, rb) : __shfl(rv1, rb & 63); \
        bool aeld = (mua < mub) || (mua == mub && rva <= rvb); \
        int eld = aeld ? ra : rb, yng = aeld ? rb : ra; \
        float byoung = aeld ? mub : mua; \
        p0 = (p0 == yng) ? eld : p0; \
        p1 = (p1 == yng) ? eld : p1; \
        if (lane == 0 && np < PAIRCAP - 1) spairs[np] = make_float2(byoung, __uint_as_float(wb)); \
        np++; \
      } }
    KBATCH(0) KBATCH(1) KBATCH(2) KBATCH(3) KBATCH(4) KBATCH(5) KBATCH(6) KBATCH(7)
#undef KBATCH
    if (np > PAIRCAP - 1) np = PAIRCAP - 1;
    if (lane == 0) {
      spairs[np] = make_float2(__uint_as_float(fminb), __uint_as_float(fmaxb));  // essential pair
      c_np = np + 1;
    }
  }
  __syncthreads();

  // ---- landscape (top-2 triangles at 25 t's) ----
  int totp = c_np;
  if (tid < 25) {
    float tv = 1.875f * (float)tid;  // linspace(0,45,25)
    float top1 = 0.f, top2 = 0.f;
    for (int i = 0; i < totp; ++i) {
      float2 p = spairs[i];
      float tri = fminf(tv - p.x, p.y - tv);
      tri = fmaxf(tri, 0.f);
      if (tri > top1) { top2 = top1; top1 = tri; }
      else if (tri > top2) top2 = tri;
    }
    sland[tid] = top1;
    sland[25 + tid] = top2;
  }
  __syncthreads();

  // ---- x = land @ Wg.T + bg (weights in LDS) ----
  if (tid < 50) {
    float acc = sbg[tid];
    for (int k = 0; k < 50; ++k) acc += sland[k] * sWg[tid * 50 + k];
    sx[tid] = acc;
  }
  __syncthreads();

  // ---- outputs: out[0:20] per-batch rows; out[20:70] signal via atomicAdd (out zeroed by memset) ----
  if (tid < 50) atomicAdd(&out[20 + tid], fabsf(sx[tid]));
  if (tid >= 64 && tid < 74) {
    int c = tid - 64;
    float acc = sbfc[c];
    for (int o = 0; o < 50; ++o) acc += fmaxf(sx[o], 0.f) * sWfc[c * 50 + o];
    out[b * 10 + c] = acc;
  }
}

extern "C" void kernel_launch(void* const* d_in, const int* in_sizes, int n_in,
                              void* d_out, int out_size, void* d_ws, size_t ws_size,
                              hipStream_t stream) {
  (void)in_sizes; (void)n_in; (void)out_size; (void)ws_size;
  const float* input = (const float*)d_in[0];
  const float* Wg  = (const float*)d_in[1];
  const float* bg  = (const float*)d_in[2];
  const float* Wfc = (const float*)d_in[3];
  const float* bfc = (const float*)d_in[4];
  float* out = (float*)d_out;

  float* f_ws = (float*)d_ws;  // 2*4096 f32

  hipMemsetAsync(out, 0, 70 * sizeof(float), stream);  // signal accumulated via atomicAdd
  dtm_kernel<<<dim3(256, 2), 1024, 0, stream>>>(input, f_ws);
  ph_kernel<<<dim3(2), 1024, 0, stream>>>(f_ws, Wg, bg, Wfc, bfc, out);
}